// Round 2
// baseline (953.881 us; speedup 1.0000x reference)
//
#include <hip/hip_runtime.h>
#include <cstdint>
#include <cstddef>

#define EDGES 800000
#define NODES 50000
#define NTILES 3125

typedef short bf16x8 __attribute__((ext_vector_type(8)));
typedef float f32x4 __attribute__((ext_vector_type(4)));
typedef uint32_t u32x4 __attribute__((ext_vector_type(4)));

__device__ __forceinline__ short f2bf(float v) {
  uint32_t u = __builtin_bit_cast(uint32_t, v);
  u = (u + 0x7FFFu + ((u >> 16) & 1u)) >> 16;
  return (short)u;
}
__device__ __forceinline__ uint32_t pack2(float lo, float hi) {
  return ((uint32_t)(uint16_t)f2bf(hi) << 16) | (uint32_t)(uint16_t)f2bf(lo);
}
__device__ __forceinline__ float silu_f(float v) {
  return v * (1.0f / (1.0f + __expf(-v)));
}

// Stage Weff^T into LDS as bf16 [j=0..127][k=0..159], row stride 168 shorts.
// Weff rows 0..127 = W1 rows; rows 128..159 = We2 @ W1[128:160,:] (edge-MLP
// layer-2 folded). Also effective bias1 into ldsb.
__device__ __forceinline__ void stage_weff(short* ldsw, float* ldsb,
                                           const float* __restrict__ W1,
                                           const float* __restrict__ We2,
                                           const float* __restrict__ b1,
                                           const float* __restrict__ be2) {
  const int t = (int)threadIdx.x;  // 512 threads
  const int j = t >> 2, kq = (t & 3) * 40;
  float wcol[32];
  if ((t & 3) == 3) {
#pragma unroll
    for (int cc = 0; cc < 32; ++cc) wcol[cc] = W1[(128 + cc) * 128 + j];
  }
  for (int kk = 0; kk < 40; ++kk) {
    const int k = kq + kk;
    float val;
    if (k < 128) {
      val = W1[k * 128 + j];
    } else {
      float s = 0.f;
#pragma unroll
      for (int cc = 0; cc < 32; ++cc) s = fmaf(We2[(k - 128) * 32 + cc], wcol[cc], s);
      val = s;
    }
    ldsw[j * 168 + k] = f2bf(val);
  }
  if (t < 128) {
    float s = b1[t];
#pragma unroll
    for (int cc = 0; cc < 32; ++cc) s = fmaf(be2[cc], W1[(128 + cc) * 128 + t], s);
    ldsb[t] = s;
  }
}

__global__ void k_init(const float* __restrict__ h, const float* __restrict__ x,
                       float* __restrict__ out) {
  const int i = (int)(blockIdx.x * 256 + threadIdx.x);
  if (i < 800000) {
    ((f32x4*)out)[i] = ((const f32x4*)h)[i];
  } else if (i < 837500) {
    ((f32x4*)out)[i] = ((const f32x4*)x)[i - 800000];
  }
}

__global__ __launch_bounds__(512, 4) void k_node(
    const float* __restrict__ h, const float* __restrict__ edist,
    const float* __restrict__ We1, const float* __restrict__ be1,
    const float* __restrict__ We2, const float* __restrict__ be2,
    const float* __restrict__ Wn1, const float* __restrict__ bn1,
    const float* __restrict__ Wn2, const float* __restrict__ bn2,
    const int* __restrict__ eidx, float* __restrict__ out) {
  __shared__ __align__(16) short ldsw[128 * 168];
  __shared__ __align__(16) short w2t[64 * 136];
  __shared__ __align__(16) float ldsb[128];
  stage_weff(ldsw, ldsb, Wn1, We2, bn1, be2);
  {
    const int t = (int)threadIdx.x;
    const int col = t >> 3, kp = (t & 7) * 16;
    for (int jj = 0; jj < 16; ++jj)
      w2t[col * 136 + kp + jj] = f2bf(Wn2[(kp + jj) * 64 + col]);
  }
  __syncthreads();

  const int tid = (int)threadIdx.x;
  const int w = tid >> 6, l = tid & 63, g = l >> 4, c = l & 15;

  float we1s[8], be1s[8];
#pragma unroll
  for (int j = 0; j < 8; ++j) { we1s[j] = We1[g * 8 + j]; be1s[j] = be1[g * 8 + j]; }
  float bias2[4];
#pragma unroll
  for (int nt = 0; nt < 4; ++nt) bias2[nt] = bn2[nt * 16 + c];

  const int srcA = (((2 * g) & 3) << 4) | c;
  const int srcB = (((2 * g + 1) & 3) << 4) | c;
  const bool hiSel = (g >= 2);
  const int arow = c * 168 + g * 8;  // shorts
  const f32x4 vzero = {0.f, 0.f, 0.f, 0.f};

  for (int t = (int)blockIdx.x; t < NTILES; t += (int)gridDim.x) {
    const int base = t * 256 + w * 32;
    const int e0 = base + c, e1 = e0 + 16;
    const int s0 = eidx[e0], s1 = eidx[e1];
    const int d0 = eidx[EDGES + e0], d1 = eidx[EDGES + e1];
    const float dd0 = edist[e0], dd1 = edist[e1];

    f32x4 acc1[8][2];
#pragma unroll
    for (int mt = 0; mt < 8; ++mt) { acc1[mt][0] = vzero; acc1[mt][1] = vzero; }

#pragma unroll
    for (int kt = 0; kt < 5; ++kt) {
      bf16x8 b0, b1;
      if (kt < 4) {
        const float* r0 = h + (size_t)((kt < 2) ? s0 : d0) * 64 + (kt & 1) * 32 + g * 8;
        const float* r1 = h + (size_t)((kt < 2) ? s1 : d1) * 64 + (kt & 1) * 32 + g * 8;
        const f32x4 pa = *(const f32x4*)r0, pb = *(const f32x4*)(r0 + 4);
        const f32x4 qa = *(const f32x4*)r1, qb = *(const f32x4*)(r1 + 4);
        u32x4 u0 = {pack2(pa[0], pa[1]), pack2(pa[2], pa[3]),
                    pack2(pb[0], pb[1]), pack2(pb[2], pb[3])};
        u32x4 u1 = {pack2(qa[0], qa[1]), pack2(qa[2], qa[3]),
                    pack2(qb[0], qb[1]), pack2(qb[2], qb[3])};
        b0 = __builtin_bit_cast(bf16x8, u0);
        b1 = __builtin_bit_cast(bf16x8, u1);
      } else {
        float t0[8], t1[8];
#pragma unroll
        for (int jt = 0; jt < 8; ++jt) {
          t0[jt] = silu_f(fmaf(dd0, we1s[jt], be1s[jt]));
          t1[jt] = silu_f(fmaf(dd1, we1s[jt], be1s[jt]));
        }
        u32x4 u0 = {pack2(t0[0], t0[1]), pack2(t0[2], t0[3]),
                    pack2(t0[4], t0[5]), pack2(t0[6], t0[7])};
        u32x4 u1 = {pack2(t1[0], t1[1]), pack2(t1[2], t1[3]),
                    pack2(t1[4], t1[5]), pack2(t1[6], t1[7])};
        b0 = __builtin_bit_cast(bf16x8, u0);
        b1 = __builtin_bit_cast(bf16x8, u1);
      }
#pragma unroll
      for (int mt = 0; mt < 8; ++mt) {
        const bf16x8 a = *(const bf16x8*)&ldsw[mt * 2688 + arow + kt * 32];
        acc1[mt][0] = __builtin_amdgcn_mfma_f32_16x16x32_bf16(a, b0, acc1[mt][0], 0, 0, 0);
        acc1[mt][1] = __builtin_amdgcn_mfma_f32_16x16x32_bf16(a, b1, acc1[mt][1], 0, 0, 0);
      }
    }

    // bias + silu + pack pairs (hid r-pairs are lane-local in swapped layout)
    uint32_t pk[2][8][2];
#pragma unroll
    for (int mt = 0; mt < 8; ++mt) {
      const f32x4 bb = *(const f32x4*)&ldsb[mt * 16 + g * 4];
#pragma unroll
      for (int n = 0; n < 2; ++n) {
        const float v0 = silu_f(acc1[mt][n][0] + bb[0]);
        const float v1 = silu_f(acc1[mt][n][1] + bb[1]);
        const float v2 = silu_f(acc1[mt][n][2] + bb[2]);
        const float v3 = silu_f(acc1[mt][n][3] + bb[3]);
        pk[n][mt][0] = pack2(v0, v1);
        pk[n][mt][1] = pack2(v2, v3);
      }
    }

    // in-register transpose: A2-frag word i <- quarter (2g+(i>>1))&3,
    // register pk[2*kt2+(g>>1)][i&1]
    bf16x8 A2[2][4];
#pragma unroll
    for (int n = 0; n < 2; ++n)
#pragma unroll
      for (int kt2 = 0; kt2 < 4; ++kt2) {
        const uint32_t eA0 = (uint32_t)__shfl((int)pk[n][2 * kt2][0], srcA);
        const uint32_t oA0 = (uint32_t)__shfl((int)pk[n][2 * kt2 + 1][0], srcA);
        const uint32_t eA1 = (uint32_t)__shfl((int)pk[n][2 * kt2][1], srcA);
        const uint32_t oA1 = (uint32_t)__shfl((int)pk[n][2 * kt2 + 1][1], srcA);
        const uint32_t eB0 = (uint32_t)__shfl((int)pk[n][2 * kt2][0], srcB);
        const uint32_t oB0 = (uint32_t)__shfl((int)pk[n][2 * kt2 + 1][0], srcB);
        const uint32_t eB1 = (uint32_t)__shfl((int)pk[n][2 * kt2][1], srcB);
        const uint32_t oB1 = (uint32_t)__shfl((int)pk[n][2 * kt2 + 1][1], srcB);
        u32x4 wv = {hiSel ? oA0 : eA0, hiSel ? oA1 : eA1,
                    hiSel ? oB0 : eB0, hiSel ? oB1 : eB1};
        A2[n][kt2] = __builtin_bit_cast(bf16x8, wv);
      }

    f32x4 acc2[2][4];
#pragma unroll
    for (int nt2 = 0; nt2 < 4; ++nt2) { acc2[0][nt2] = vzero; acc2[1][nt2] = vzero; }
#pragma unroll
    for (int kt2 = 0; kt2 < 4; ++kt2)
#pragma unroll
      for (int nt2 = 0; nt2 < 4; ++nt2) {
        const bf16x8 b2 = *(const bf16x8*)&w2t[(nt2 * 16 + c) * 136 + kt2 * 32 + g * 8];
        acc2[0][nt2] = __builtin_amdgcn_mfma_f32_16x16x32_bf16(A2[0][kt2], b2, acc2[0][nt2], 0, 0, 0);
        acc2[1][nt2] = __builtin_amdgcn_mfma_f32_16x16x32_bf16(A2[1][kt2], b2, acc2[1][nt2], 0, 0, 0);
      }

#pragma unroll
    for (int n = 0; n < 2; ++n) {
      const int dn = n ? d1 : d0;
#pragma unroll
      for (int r = 0; r < 4; ++r) {
        const int de = __shfl(dn, g * 4 + r);
#pragma unroll
        for (int nt2 = 0; nt2 < 4; ++nt2)
          unsafeAtomicAdd(&out[de * 64 + nt2 * 16 + c], acc2[n][nt2][r] + bias2[nt2]);
      }
    }
  }
}

__global__ __launch_bounds__(512, 4) void k_coord(
    const float* __restrict__ h, const float* __restrict__ x,
    const float* __restrict__ edist,
    const float* __restrict__ We1, const float* __restrict__ be1,
    const float* __restrict__ We2, const float* __restrict__ be2,
    const float* __restrict__ Wc1, const float* __restrict__ bc1,
    const float* __restrict__ Wc2,
    const int* __restrict__ eidx, float* __restrict__ xo) {
  __shared__ __align__(16) short ldsw[128 * 168];
  __shared__ __align__(16) float ldsb[128];
  __shared__ __align__(16) float ldsc[128];
  stage_weff(ldsw, ldsb, Wc1, We2, bc1, be2);
  if (threadIdx.x < 128) ldsc[threadIdx.x] = Wc2[threadIdx.x];
  __syncthreads();

  const int tid = (int)threadIdx.x;
  const int w = tid >> 6, l = tid & 63, g = l >> 4, c = l & 15;

  float we1s[8], be1s[8];
#pragma unroll
  for (int j = 0; j < 8; ++j) { we1s[j] = We1[g * 8 + j]; be1s[j] = be1[g * 8 + j]; }

  const int arow = c * 168 + g * 8;
  const f32x4 vzero = {0.f, 0.f, 0.f, 0.f};

  for (int t = (int)blockIdx.x; t < NTILES; t += (int)gridDim.x) {
    const int base = t * 256 + w * 32;
    const int e0 = base + c, e1 = e0 + 16;
    const int s0 = eidx[e0], s1 = eidx[e1];
    const int d0 = eidx[EDGES + e0], d1 = eidx[EDGES + e1];
    const float dd0 = edist[e0], dd1 = edist[e1];

    f32x4 acc1[8][2];
#pragma unroll
    for (int mt = 0; mt < 8; ++mt) { acc1[mt][0] = vzero; acc1[mt][1] = vzero; }

#pragma unroll
    for (int kt = 0; kt < 5; ++kt) {
      bf16x8 b0, b1;
      if (kt < 4) {
        const float* r0 = h + (size_t)((kt < 2) ? s0 : d0) * 64 + (kt & 1) * 32 + g * 8;
        const float* r1 = h + (size_t)((kt < 2) ? s1 : d1) * 64 + (kt & 1) * 32 + g * 8;
        const f32x4 pa = *(const f32x4*)r0, pb = *(const f32x4*)(r0 + 4);
        const f32x4 qa = *(const f32x4*)r1, qb = *(const f32x4*)(r1 + 4);
        u32x4 u0 = {pack2(pa[0], pa[1]), pack2(pa[2], pa[3]),
                    pack2(pb[0], pb[1]), pack2(pb[2], pb[3])};
        u32x4 u1 = {pack2(qa[0], qa[1]), pack2(qa[2], qa[3]),
                    pack2(qb[0], qb[1]), pack2(qb[2], qb[3])};
        b0 = __builtin_bit_cast(bf16x8, u0);
        b1 = __builtin_bit_cast(bf16x8, u1);
      } else {
        float t0[8], t1[8];
#pragma unroll
        for (int jt = 0; jt < 8; ++jt) {
          t0[jt] = silu_f(fmaf(dd0, we1s[jt], be1s[jt]));
          t1[jt] = silu_f(fmaf(dd1, we1s[jt], be1s[jt]));
        }
        u32x4 u0 = {pack2(t0[0], t0[1]), pack2(t0[2], t0[3]),
                    pack2(t0[4], t0[5]), pack2(t0[6], t0[7])};
        u32x4 u1 = {pack2(t1[0], t1[1]), pack2(t1[2], t1[3]),
                    pack2(t1[4], t1[5]), pack2(t1[6], t1[7])};
        b0 = __builtin_bit_cast(bf16x8, u0);
        b1 = __builtin_bit_cast(bf16x8, u1);
      }
#pragma unroll
      for (int mt = 0; mt < 8; ++mt) {
        const bf16x8 a = *(const bf16x8*)&ldsw[mt * 2688 + arow + kt * 32];
        acc1[mt][0] = __builtin_amdgcn_mfma_f32_16x16x32_bf16(a, b0, acc1[mt][0], 0, 0, 0);
        acc1[mt][1] = __builtin_amdgcn_mfma_f32_16x16x32_bf16(a, b1, acc1[mt][1], 0, 0, 0);
      }
    }

    float p0 = 0.f, p1 = 0.f;
#pragma unroll
    for (int mt = 0; mt < 8; ++mt) {
      const f32x4 bb = *(const f32x4*)&ldsb[mt * 16 + g * 4];
      const f32x4 ww = *(const f32x4*)&ldsc[mt * 16 + g * 4];
#pragma unroll
      for (int r = 0; r < 4; ++r) {
        p0 += silu_f(acc1[mt][0][r] + bb[r]) * ww[r];
        p1 += silu_f(acc1[mt][1][r] + bb[r]) * ww[r];
      }
    }
    p0 += __shfl_xor(p0, 16); p0 += __shfl_xor(p0, 32);
    p1 += __shfl_xor(p1, 16); p1 += __shfl_xor(p1, 32);

    if (g < 2) {
      const float cw = g ? p1 : p0;
      const int se = g ? s1 : s0;
      const int de = g ? d1 : d0;
      const float ax = x[se * 3 + 0] - x[de * 3 + 0];
      const float ay = x[se * 3 + 1] - x[de * 3 + 1];
      const float az = x[se * 3 + 2] - x[de * 3 + 2];
      float len = sqrtf(fmaf(ax, ax, fmaf(ay, ay, az * az)));
      len = fmaxf(len, 1e-8f);
      const float scl = cw / len;
      unsafeAtomicAdd(&xo[de * 3 + 0], scl * ax);
      unsafeAtomicAdd(&xo[de * 3 + 1], scl * ay);
      unsafeAtomicAdd(&xo[de * 3 + 2], scl * az);
    }
  }
}

extern "C" void kernel_launch(void* const* d_in, const int* in_sizes, int n_in,
                              void* d_out, int out_size, void* d_ws, size_t ws_size,
                              hipStream_t stream) {
  const float* h = (const float*)d_in[0];
  const float* x = (const float*)d_in[1];
  const float* edist = (const float*)d_in[2];
  const float* We1 = (const float*)d_in[3];
  const float* be1 = (const float*)d_in[4];
  const float* We2 = (const float*)d_in[5];
  const float* be2 = (const float*)d_in[6];
  const float* Wn1 = (const float*)d_in[7];
  const float* bn1 = (const float*)d_in[8];
  const float* Wn2 = (const float*)d_in[9];
  const float* bn2 = (const float*)d_in[10];
  const float* Wc1 = (const float*)d_in[11];
  const float* bc1 = (const float*)d_in[12];
  const float* Wc2 = (const float*)d_in[13];
  const int* eidx = (const int*)d_in[14];
  float* out = (float*)d_out;
  float* xo = out + 3200000;

  k_init<<<dim3(3272), dim3(256), 0, stream>>>(h, x, out);
  k_node<<<dim3(512), dim3(512), 0, stream>>>(h, edist, We1, be1, We2, be2, Wn1, bn1,
                                              Wn2, bn2, eidx, out);
  k_coord<<<dim3(512), dim3(512), 0, stream>>>(h, x, edist, We1, be1, We2, be2, Wc1,
                                               bc1, Wc2, eidx, xo);
}

// Round 3
// 812.622 us; speedup vs baseline: 1.1738x; 1.1738x over previous
//
#include <hip/hip_runtime.h>
#include <cstdint>
#include <cstddef>

#define E_CNT 800000
#define N_CNT 50000
#define NT 3125

typedef short bf16x8 __attribute__((ext_vector_type(8)));
typedef short s16x4 __attribute__((ext_vector_type(4)));
typedef float f32x4 __attribute__((ext_vector_type(4)));
typedef uint32_t u32x4 __attribute__((ext_vector_type(4)));

__device__ __forceinline__ short f2bf(float v) {
  uint32_t u = __builtin_bit_cast(uint32_t, v);
  u = (u + 0x7FFFu + ((u >> 16) & 1u)) >> 16;
  return (short)u;
}
__device__ __forceinline__ uint32_t pack2(float lo, float hi) {
  return ((uint32_t)(uint16_t)f2bf(hi) << 16) | (uint32_t)(uint16_t)f2bf(lo);
}
__device__ __forceinline__ float silu_f(float v) {
  return v * (1.0f / (1.0f + __expf(-v)));
}

// Weight fragment read: row-major [128 rows][160 k] bf16, stride 160 shorts,
// XOR-swizzled per 8-short chunk (key from row&7; tail uses row&3 to stay in range).
__device__ __forceinline__ bf16x8 ldw_frag(const short* ldsw, int row, int kt, int g, int c) {
  const int koff = kt * 32 + g * 8;
  const int swz = (kt < 4) ? ((c & 7) << 3) : ((c & 3) << 3);
  return *(const bf16x8*)&ldsw[row * 160 + (koff ^ swz)];
}

// Stage Weff^T (edge-MLP layer-2 folded into rows 128..159) + effective bias1.
__device__ __forceinline__ void stage_weff(short* ldsw, float* ldsb1,
                                           const float* __restrict__ W1,
                                           const float* __restrict__ We2,
                                           const float* __restrict__ b1,
                                           const float* __restrict__ be2) {
  const int t = (int)threadIdx.x;  // 512 threads
  const int j = t >> 2, kq = (t & 3) * 40;
  float wcol[32];
  if ((t & 3) == 3) {
#pragma unroll
    for (int cc = 0; cc < 32; ++cc) wcol[cc] = W1[(128 + cc) * 128 + j];
  }
  for (int kk = 0; kk < 40; ++kk) {
    const int k = kq + kk;
    float val;
    if (k < 128) {
      val = W1[k * 128 + j];
    } else {
      float s = 0.f;
#pragma unroll
      for (int cc = 0; cc < 32; ++cc) s = fmaf(We2[(k - 128) * 32 + cc], wcol[cc], s);
      val = s;
    }
    const int koff = k & ~7;
    const int swz = (koff < 128) ? ((j & 7) << 3) : ((j & 3) << 3);
    ldsw[j * 160 + (koff ^ swz) + (k & 7)] = f2bf(val);
  }
  if (t < 128) {
    float s = b1[t];
#pragma unroll
    for (int cc = 0; cc < 32; ++cc) s = fmaf(be2[cc], W1[(128 + cc) * 128 + t], s);
    ldsb1[t] = s;
  }
}

__global__ void k_init(const float* __restrict__ h, const float* __restrict__ x,
                       float* __restrict__ out, short* __restrict__ hb) {
  const int i = (int)(blockIdx.x * 256 + threadIdx.x);
  if (i < 800000) {
    const f32x4 v = ((const f32x4*)h)[i];
    ((f32x4*)out)[i] = v;
    if (hb) {
      s16x4 p;
#pragma unroll
      for (int j = 0; j < 4; ++j) p[j] = f2bf(v[j]);
      *(s16x4*)(hb + i * 4) = p;
    }
  } else if (i < 837500) {
    ((f32x4*)out)[i] = ((const f32x4*)x)[i - 800000];
  }
}

__global__ void k_hist(const int* __restrict__ eidx, int* __restrict__ cursor) {
  const int e = (int)(blockIdx.x * 256 + threadIdx.x);
  if (e < E_CNT) atomicAdd(&cursor[eidx[E_CNT + e]], 1);
}

__global__ __launch_bounds__(1024) void k_scan(int* __restrict__ cursor) {
  __shared__ int part[1024];
  const int t = (int)threadIdx.x;
  const int b0 = t * 49;
  int n = N_CNT - b0;
  n = n < 0 ? 0 : (n > 49 ? 49 : n);
  int s = 0;
  for (int i = 0; i < n; ++i) s += cursor[b0 + i];
  part[t] = s;
  __syncthreads();
  for (int off = 1; off < 1024; off <<= 1) {
    const int u = (t >= off) ? part[t - off] : 0;
    __syncthreads();
    part[t] += u;
    __syncthreads();
  }
  int run = (t == 0) ? 0 : part[t - 1];
  for (int i = 0; i < n; ++i) {
    const int old = cursor[b0 + i];
    cursor[b0 + i] = run;
    run += old;
  }
}

__global__ void k_fill(const int* __restrict__ eidx, const float* __restrict__ edist,
                       int* __restrict__ cursor, int* __restrict__ src_s,
                       int* __restrict__ dst_s, float* __restrict__ dist_s) {
  const int e = (int)(blockIdx.x * 256 + threadIdx.x);
  if (e < E_CNT) {
    const int d = eidx[E_CNT + e];
    const int pos = atomicAdd(&cursor[d], 1);
    src_s[pos] = eidx[e];
    dst_s[pos] = d;
    dist_s[pos] = edist[e];
  }
}

template <bool SORTED>
__global__ __launch_bounds__(512) __attribute__((amdgpu_waves_per_eu(4, 4)))
void k_node(const float* __restrict__ h, const short* __restrict__ hb,
            const float* __restrict__ edist,
            const float* __restrict__ We1, const float* __restrict__ be1,
            const float* __restrict__ We2, const float* __restrict__ be2,
            const float* __restrict__ Wn1, const float* __restrict__ bn1,
            const float* __restrict__ Wn2, const float* __restrict__ bn2,
            const int* __restrict__ eidx,
            const int* __restrict__ src_s, const int* __restrict__ dst_s,
            const float* __restrict__ dist_s, float* __restrict__ out) {
  __shared__ __align__(16) short ldsw[128 * 160];   // 40960 B
  __shared__ __align__(16) short scr[8][16 * 136];  // 34816 B
  __shared__ float ldsb1[128];
  __shared__ float ldse1w[32];
  __shared__ float ldse1b[32];
  stage_weff(ldsw, ldsb1, Wn1, We2, bn1, be2);
  if (threadIdx.x < 32) {
    ldse1w[threadIdx.x] = We1[threadIdx.x];
    ldse1b[threadIdx.x] = be1[threadIdx.x];
  }

  const int tid = (int)threadIdx.x;
  const int w = tid >> 6, l = tid & 63, g = l >> 4, c = l & 15;
  short* myscr = &scr[w][0];

  bf16x8 wf[4][4];
#pragma unroll
  for (int nt2 = 0; nt2 < 4; ++nt2)
#pragma unroll
    for (int kt2 = 0; kt2 < 4; ++kt2) {
      bf16x8 v;
#pragma unroll
      for (int j = 0; j < 8; ++j)
        v[j] = f2bf(Wn2[(kt2 * 32 + g * 8 + j) * 64 + nt2 * 16 + c]);
      wf[nt2][kt2] = v;
    }
  float bias2r[4];
#pragma unroll
  for (int nt2 = 0; nt2 < 4; ++nt2) bias2r[nt2] = bn2[nt2 * 16 + c];
  __syncthreads();

  const f32x4 vzero = {0.f, 0.f, 0.f, 0.f};

  for (int t = (int)blockIdx.x; t < NT; t += (int)gridDim.x) {
    const int base = t * 256 + w * 32;
    // slot remap: quarter g owns edges base+g*8 .. base+g*8+7 (consecutive)
    const int e0 = base + ((c >> 2) << 3) + (c & 3);
    const int e1 = e0 + 4;
    int s0, s1, d0, d1;
    float dd0, dd1;
    if (SORTED) {
      s0 = src_s[e0]; s1 = src_s[e1];
      d0 = dst_s[e0]; d1 = dst_s[e1];
      dd0 = dist_s[e0]; dd1 = dist_s[e1];
    } else {
      s0 = eidx[e0]; s1 = eidx[e1];
      d0 = eidx[E_CNT + e0]; d1 = eidx[E_CNT + e1];
      dd0 = edist[e0]; dd1 = edist[e1];
    }

    f32x4 acc1[8][2];
#pragma unroll
    for (int nt = 0; nt < 8; ++nt) { acc1[nt][0] = vzero; acc1[nt][1] = vzero; }

#pragma unroll
    for (int kt = 0; kt < 5; ++kt) {
      bf16x8 a0, a1;
      if (kt < 4) {
        const size_t r0 = (size_t)((kt < 2) ? s0 : d0) * 64 + (kt & 1) * 32 + g * 8;
        const size_t r1 = (size_t)((kt < 2) ? s1 : d1) * 64 + (kt & 1) * 32 + g * 8;
        if (SORTED) {
          a0 = *(const bf16x8*)&hb[r0];
          a1 = *(const bf16x8*)&hb[r1];
        } else {
          const f32x4 pa = *(const f32x4*)(h + r0), pb = *(const f32x4*)(h + r0 + 4);
          const f32x4 qa = *(const f32x4*)(h + r1), qb = *(const f32x4*)(h + r1 + 4);
          u32x4 u0 = {pack2(pa[0], pa[1]), pack2(pa[2], pa[3]),
                      pack2(pb[0], pb[1]), pack2(pb[2], pb[3])};
          u32x4 u1 = {pack2(qa[0], qa[1]), pack2(qa[2], qa[3]),
                      pack2(qb[0], qb[1]), pack2(qb[2], qb[3])};
          a0 = __builtin_bit_cast(bf16x8, u0);
          a1 = __builtin_bit_cast(bf16x8, u1);
        }
      } else {
        float t0[8], t1[8];
#pragma unroll
        for (int j = 0; j < 8; ++j) {
          const float wv = ldse1w[g * 8 + j], bv = ldse1b[g * 8 + j];
          t0[j] = silu_f(fmaf(dd0, wv, bv));
          t1[j] = silu_f(fmaf(dd1, wv, bv));
        }
        u32x4 u0 = {pack2(t0[0], t0[1]), pack2(t0[2], t0[3]),
                    pack2(t0[4], t0[5]), pack2(t0[6], t0[7])};
        u32x4 u1 = {pack2(t1[0], t1[1]), pack2(t1[2], t1[3]),
                    pack2(t1[4], t1[5]), pack2(t1[6], t1[7])};
        a0 = __builtin_bit_cast(bf16x8, u0);
        a1 = __builtin_bit_cast(bf16x8, u1);
      }
#pragma unroll
      for (int nt = 0; nt < 8; ++nt) {
        const bf16x8 b = ldw_frag(ldsw, nt * 16 + c, kt, g, c);
        acc1[nt][0] = __builtin_amdgcn_mfma_f32_16x16x32_bf16(a0, b, acc1[nt][0], 0, 0, 0);
        acc1[nt][1] = __builtin_amdgcn_mfma_f32_16x16x32_bf16(a1, b, acc1[nt][1], 0, 0, 0);
      }
    }

    f32x4 acc2[2][4];
#pragma unroll
    for (int nt2 = 0; nt2 < 4; ++nt2) { acc2[0][nt2] = vzero; acc2[1][nt2] = vzero; }

#pragma unroll
    for (int n = 0; n < 2; ++n) {
#pragma unroll
      for (int nt = 0; nt < 8; ++nt) {
        const float bia = ldsb1[nt * 16 + c];
#pragma unroll
        for (int r = 0; r < 4; ++r)
          myscr[(g * 4 + r) * 136 + nt * 16 + c] = f2bf(silu_f(acc1[nt][n][r] + bia));
      }
#pragma unroll
      for (int kt2 = 0; kt2 < 4; ++kt2) {
        const bf16x8 a2 = *(const bf16x8*)&myscr[c * 136 + kt2 * 32 + g * 8];
#pragma unroll
        for (int nt2 = 0; nt2 < 4; ++nt2)
          acc2[n][nt2] = __builtin_amdgcn_mfma_f32_16x16x32_bf16(a2, wf[nt2][kt2], acc2[n][nt2], 0, 0, 0);
      }
    }

    // run-length-reduced atomics over the quarter's 8 consecutive edges
    int des[8];
#pragma unroll
    for (int s2 = 0; s2 < 4; ++s2) {
      des[s2] = __shfl(d0, 4 * g + s2);
      des[4 + s2] = __shfl(d1, 4 * g + s2);
    }
    float run[4];
    int cur = des[0];
#pragma unroll
    for (int nt2 = 0; nt2 < 4; ++nt2) run[nt2] = acc2[0][nt2][0] + bias2r[nt2];
#pragma unroll
    for (int s = 1; s < 8; ++s) {
      const int n = s >> 2, r = s & 3;
      if (des[s] == cur) {
#pragma unroll
        for (int nt2 = 0; nt2 < 4; ++nt2) run[nt2] += acc2[n][nt2][r] + bias2r[nt2];
      } else {
#pragma unroll
        for (int nt2 = 0; nt2 < 4; ++nt2)
          unsafeAtomicAdd(&out[(size_t)cur * 64 + nt2 * 16 + c], run[nt2]);
        cur = des[s];
#pragma unroll
        for (int nt2 = 0; nt2 < 4; ++nt2) run[nt2] = acc2[n][nt2][r] + bias2r[nt2];
      }
    }
#pragma unroll
    for (int nt2 = 0; nt2 < 4; ++nt2)
      unsafeAtomicAdd(&out[(size_t)cur * 64 + nt2 * 16 + c], run[nt2]);
  }
}

template <bool BF>
__global__ __launch_bounds__(512) __attribute__((amdgpu_waves_per_eu(4, 4)))
void k_coord(const float* __restrict__ h, const short* __restrict__ hb,
             const float* __restrict__ x, const float* __restrict__ edist,
             const float* __restrict__ We1, const float* __restrict__ be1,
             const float* __restrict__ We2, const float* __restrict__ be2,
             const float* __restrict__ Wc1, const float* __restrict__ bc1,
             const float* __restrict__ Wc2,
             const int* __restrict__ eidx, float* __restrict__ xo) {
  __shared__ __align__(16) short ldsw[128 * 160];
  __shared__ float ldsb1[128];
  __shared__ float ldsc[128];
  __shared__ float ldse1w[32];
  __shared__ float ldse1b[32];
  stage_weff(ldsw, ldsb1, Wc1, We2, bc1, be2);
  if (threadIdx.x < 128) ldsc[threadIdx.x] = Wc2[threadIdx.x];
  if (threadIdx.x < 32) {
    ldse1w[threadIdx.x] = We1[threadIdx.x];
    ldse1b[threadIdx.x] = be1[threadIdx.x];
  }
  __syncthreads();

  const int tid = (int)threadIdx.x;
  const int w = tid >> 6, l = tid & 63, g = l >> 4, c = l & 15;
  const f32x4 vzero = {0.f, 0.f, 0.f, 0.f};

  for (int t = (int)blockIdx.x; t < NT; t += (int)gridDim.x) {
    const int base = t * 256 + w * 32;
    const int e0 = base + c, e1 = e0 + 16;
    const int s0 = eidx[e0], s1 = eidx[e1];
    const int d0 = eidx[E_CNT + e0], d1 = eidx[E_CNT + e1];
    const float dd0 = edist[e0], dd1 = edist[e1];

    f32x4 acc1[8][2];
#pragma unroll
    for (int mt = 0; mt < 8; ++mt) { acc1[mt][0] = vzero; acc1[mt][1] = vzero; }

#pragma unroll
    for (int kt = 0; kt < 5; ++kt) {
      bf16x8 b0, b1;
      if (kt < 4) {
        const size_t r0 = (size_t)((kt < 2) ? s0 : d0) * 64 + (kt & 1) * 32 + g * 8;
        const size_t r1 = (size_t)((kt < 2) ? s1 : d1) * 64 + (kt & 1) * 32 + g * 8;
        if (BF) {
          b0 = *(const bf16x8*)&hb[r0];
          b1 = *(const bf16x8*)&hb[r1];
        } else {
          const f32x4 pa = *(const f32x4*)(h + r0), pb = *(const f32x4*)(h + r0 + 4);
          const f32x4 qa = *(const f32x4*)(h + r1), qb = *(const f32x4*)(h + r1 + 4);
          u32x4 u0 = {pack2(pa[0], pa[1]), pack2(pa[2], pa[3]),
                      pack2(pb[0], pb[1]), pack2(pb[2], pb[3])};
          u32x4 u1 = {pack2(qa[0], qa[1]), pack2(qa[2], qa[3]),
                      pack2(qb[0], qb[1]), pack2(qb[2], qb[3])};
          b0 = __builtin_bit_cast(bf16x8, u0);
          b1 = __builtin_bit_cast(bf16x8, u1);
        }
      } else {
        float t0[8], t1[8];
#pragma unroll
        for (int j = 0; j < 8; ++j) {
          const float wv = ldse1w[g * 8 + j], bv = ldse1b[g * 8 + j];
          t0[j] = silu_f(fmaf(dd0, wv, bv));
          t1[j] = silu_f(fmaf(dd1, wv, bv));
        }
        u32x4 u0 = {pack2(t0[0], t0[1]), pack2(t0[2], t0[3]),
                    pack2(t0[4], t0[5]), pack2(t0[6], t0[7])};
        u32x4 u1 = {pack2(t1[0], t1[1]), pack2(t1[2], t1[3]),
                    pack2(t1[4], t1[5]), pack2(t1[6], t1[7])};
        b0 = __builtin_bit_cast(bf16x8, u0);
        b1 = __builtin_bit_cast(bf16x8, u1);
      }
#pragma unroll
      for (int mt = 0; mt < 8; ++mt) {
        const bf16x8 a = ldw_frag(ldsw, mt * 16 + c, kt, g, c);
        acc1[mt][0] = __builtin_amdgcn_mfma_f32_16x16x32_bf16(a, b0, acc1[mt][0], 0, 0, 0);
        acc1[mt][1] = __builtin_amdgcn_mfma_f32_16x16x32_bf16(a, b1, acc1[mt][1], 0, 0, 0);
      }
    }

    float p0 = 0.f, p1 = 0.f;
#pragma unroll
    for (int mt = 0; mt < 8; ++mt) {
      const f32x4 bb = *(const f32x4*)&ldsb1[mt * 16 + g * 4];
      const f32x4 ww = *(const f32x4*)&ldsc[mt * 16 + g * 4];
#pragma unroll
      for (int r = 0; r < 4; ++r) {
        p0 += silu_f(acc1[mt][0][r] + bb[r]) * ww[r];
        p1 += silu_f(acc1[mt][1][r] + bb[r]) * ww[r];
      }
    }
    p0 += __shfl_xor(p0, 16); p0 += __shfl_xor(p0, 32);
    p1 += __shfl_xor(p1, 16); p1 += __shfl_xor(p1, 32);

    if (g < 2) {
      const float cw = g ? p1 : p0;
      const int se = g ? s1 : s0;
      const int de = g ? d1 : d0;
      const float ax = x[se * 3 + 0] - x[de * 3 + 0];
      const float ay = x[se * 3 + 1] - x[de * 3 + 1];
      const float az = x[se * 3 + 2] - x[de * 3 + 2];
      float len = sqrtf(fmaf(ax, ax, fmaf(ay, ay, az * az)));
      len = fmaxf(len, 1e-8f);
      const float scl = cw / len;
      unsafeAtomicAdd(&xo[de * 3 + 0], scl * ax);
      unsafeAtomicAdd(&xo[de * 3 + 1], scl * ay);
      unsafeAtomicAdd(&xo[de * 3 + 2], scl * az);
    }
  }
}

extern "C" void kernel_launch(void* const* d_in, const int* in_sizes, int n_in,
                              void* d_out, int out_size, void* d_ws, size_t ws_size,
                              hipStream_t stream) {
  const float* h = (const float*)d_in[0];
  const float* x = (const float*)d_in[1];
  const float* edist = (const float*)d_in[2];
  const float* We1 = (const float*)d_in[3];
  const float* be1 = (const float*)d_in[4];
  const float* We2 = (const float*)d_in[5];
  const float* be2 = (const float*)d_in[6];
  const float* Wn1 = (const float*)d_in[7];
  const float* bn1 = (const float*)d_in[8];
  const float* Wn2 = (const float*)d_in[9];
  const float* bn2 = (const float*)d_in[10];
  const float* Wc1 = (const float*)d_in[11];
  const float* bc1 = (const float*)d_in[12];
  const float* Wc2 = (const float*)d_in[13];
  const int* eidx = (const int*)d_in[14];
  float* out = (float*)d_out;
  float* xo = out + 3200000;

  // ws layout (16-byte aligned offsets)
  char* wsb = (char*)d_ws;
  int* cursor = (int*)wsb;                          // 50000*4 -> pad 200704
  int* src_s = (int*)(wsb + 200704);                // 3.2 MB
  int* dst_s = (int*)(wsb + 3400704);               // 3.2 MB
  float* dist_s = (float*)(wsb + 6600704);          // 3.2 MB
  short* hb = (short*)(wsb + 9800704);              // 6.4 MB -> end 16200704
  const bool sorted = (ws_size >= (size_t)16200704);

  if (sorted) {
    hipMemsetAsync(cursor, 0, N_CNT * sizeof(int), stream);
    k_init<<<dim3(3272), dim3(256), 0, stream>>>(h, x, out, hb);
    k_hist<<<dim3(3125), dim3(256), 0, stream>>>(eidx, cursor);
    k_scan<<<dim3(1), dim3(1024), 0, stream>>>(cursor);
    k_fill<<<dim3(3125), dim3(256), 0, stream>>>(eidx, edist, cursor, src_s, dst_s, dist_s);
    k_node<true><<<dim3(512), dim3(512), 0, stream>>>(h, hb, edist, We1, be1, We2, be2,
                                                      Wn1, bn1, Wn2, bn2, eidx,
                                                      src_s, dst_s, dist_s, out);
    k_coord<true><<<dim3(512), dim3(512), 0, stream>>>(h, hb, x, edist, We1, be1, We2, be2,
                                                       Wc1, bc1, Wc2, eidx, xo);
  } else {
    k_init<<<dim3(3272), dim3(256), 0, stream>>>(h, x, out, nullptr);
    k_node<false><<<dim3(512), dim3(512), 0, stream>>>(h, nullptr, edist, We1, be1, We2, be2,
                                                       Wn1, bn1, Wn2, bn2, eidx,
                                                       nullptr, nullptr, nullptr, out);
    k_coord<false><<<dim3(512), dim3(512), 0, stream>>>(h, nullptr, x, edist, We1, be1, We2, be2,
                                                        Wc1, bc1, Wc2, eidx, xo);
  }
}

// Round 4
// 622.215 us; speedup vs baseline: 1.5330x; 1.3060x over previous
//
#include <hip/hip_runtime.h>
#include <cstdint>
#include <cstddef>

#define E_CNT 800000
#define N_CNT 50000
#define NT 6250  // tiles of 128 edges

typedef short bf16x8 __attribute__((ext_vector_type(8)));
typedef short s16x4 __attribute__((ext_vector_type(4)));
typedef float f32x4 __attribute__((ext_vector_type(4)));
typedef uint32_t u32x4 __attribute__((ext_vector_type(4)));

__device__ __forceinline__ short f2bf(float v) {
  uint32_t u = __builtin_bit_cast(uint32_t, v);
  u = (u + 0x7FFFu + ((u >> 16) & 1u)) >> 16;
  return (short)u;
}
__device__ __forceinline__ uint32_t pack2(float lo, float hi) {
  return ((uint32_t)(uint16_t)f2bf(hi) << 16) | (uint32_t)(uint16_t)f2bf(lo);
}
__device__ __forceinline__ float silu_f(float v) {
  return v * (1.0f / (1.0f + __expf(-v)));
}

// ---- round-1 weight staging (stride 160, XOR swizzle), 256 threads ----
__device__ __forceinline__ void stage_weights(short* lds, const float* __restrict__ W1,
                                              const float* __restrict__ We2) {
  const int t = (int)threadIdx.x;  // 256 threads
  const int col = t >> 1;          // 0..127
  const int kb = (t & 1) * 80;
  float wcol[32];
#pragma unroll
  for (int cc = 0; cc < 32; ++cc) wcol[cc] = W1[(128 + cc) * 128 + col];
#pragma unroll
  for (int ch = 0; ch < 10; ++ch) {
    const int koff = kb + ch * 8;
    bf16x8 v;
#pragma unroll
    for (int j = 0; j < 8; ++j) {
      const int k = koff + j;
      float val;
      if (k < 128) {
        val = W1[k * 128 + col];
      } else {
        float s = 0.f;
#pragma unroll
        for (int cc = 0; cc < 32; ++cc) s = fmaf(We2[(k - 128) * 32 + cc], wcol[cc], s);
        val = s;
      }
      v[j] = f2bf(val);
    }
    const int swz = (koff < 128) ? ((col & 7) << 3) : ((col & 3) << 3);
    *(bf16x8*)&lds[col * 160 + (koff ^ swz)] = v;
  }
}

__global__ void k_init(const float* __restrict__ h, const float* __restrict__ x,
                       float* __restrict__ out, short* __restrict__ hb) {
  const int i = (int)(blockIdx.x * 256 + threadIdx.x);
  if (i < 800000) {
    const f32x4 v = ((const f32x4*)h)[i];
    ((f32x4*)out)[i] = v;
    if (hb) {
      s16x4 p;
#pragma unroll
      for (int j = 0; j < 4; ++j) p[j] = f2bf(v[j]);
      *(s16x4*)(hb + i * 4) = p;
    }
  } else if (i < 837500) {
    ((f32x4*)out)[i] = ((const f32x4*)x)[i - 800000];
  }
}

__global__ void k_hist(const int* __restrict__ eidx, int* __restrict__ cursor) {
  const int e = (int)(blockIdx.x * 256 + threadIdx.x);
  if (e < E_CNT) atomicAdd(&cursor[eidx[E_CNT + e]], 1);
}

__global__ __launch_bounds__(1024) void k_scan(int* __restrict__ cursor) {
  __shared__ int part[1024];
  const int t = (int)threadIdx.x;
  const int b0 = t * 49;
  int n = N_CNT - b0;
  n = n < 0 ? 0 : (n > 49 ? 49 : n);
  int s = 0;
  for (int i = 0; i < n; ++i) s += cursor[b0 + i];
  part[t] = s;
  __syncthreads();
  for (int off = 1; off < 1024; off <<= 1) {
    const int u = (t >= off) ? part[t - off] : 0;
    __syncthreads();
    part[t] += u;
    __syncthreads();
  }
  int run = (t == 0) ? 0 : part[t - 1];
  for (int i = 0; i < n; ++i) {
    const int old = cursor[b0 + i];
    cursor[b0 + i] = run;
    run += old;
  }
}

__global__ void k_fill(const int* __restrict__ eidx, const float* __restrict__ edist,
                       int* __restrict__ cursor, int* __restrict__ src_s,
                       int* __restrict__ dst_s, float* __restrict__ dist_s) {
  const int e = (int)(blockIdx.x * 256 + threadIdx.x);
  if (e < E_CNT) {
    const int d = eidx[E_CNT + e];
    const int pos = atomicAdd(&cursor[d], 1);
    src_s[pos] = eidx[e];
    dst_s[pos] = d;
    dist_s[pos] = edist[e];
  }
}

template <bool SORTED>
__global__ __launch_bounds__(256, 2) void k_node(
    const float* __restrict__ h, const short* __restrict__ hb,
    const float* __restrict__ edist,
    const float* __restrict__ We1, const float* __restrict__ be1,
    const float* __restrict__ We2, const float* __restrict__ be2,
    const float* __restrict__ Wn1, const float* __restrict__ bn1,
    const float* __restrict__ Wn2, const float* __restrict__ bn2,
    const int* __restrict__ eidx,
    const int* __restrict__ src_s, const int* __restrict__ dst_s,
    const float* __restrict__ dist_s, float* __restrict__ out) {
  __shared__ __align__(16) short ldsw[128 * 160];
  __shared__ __align__(16) short scr[4][16 * 136];
  stage_weights(ldsw, Wn1, We2);
  __syncthreads();

  const int tid = (int)threadIdx.x;
  const int w = tid >> 6, l = tid & 63, g = l >> 4, c = l & 15;
  short* myscr = &scr[w][0];

  float we1s[8], be1s[8];
#pragma unroll
  for (int j = 0; j < 8; ++j) { we1s[j] = We1[g * 8 + j]; be1s[j] = be1[g * 8 + j]; }

  float bias1[8];
#pragma unroll
  for (int nt = 0; nt < 8; ++nt) {
    const int colf = nt * 16 + c;
    float s = bn1[colf];
    for (int cc = 0; cc < 32; ++cc) s = fmaf(be2[cc], Wn1[(128 + cc) * 128 + colf], s);
    bias1[nt] = s;
  }
  float bias2[4];
#pragma unroll
  for (int nt = 0; nt < 4; ++nt) bias2[nt] = bn2[nt * 16 + c];

  bf16x8 wf[4][4];
#pragma unroll
  for (int nt = 0; nt < 4; ++nt)
#pragma unroll
    for (int kt = 0; kt < 4; ++kt) {
      bf16x8 v;
#pragma unroll
      for (int j = 0; j < 8; ++j) v[j] = f2bf(Wn2[(kt * 32 + g * 8 + j) * 64 + nt * 16 + c]);
      wf[nt][kt] = v;
    }

  const f32x4 vzero = {0.f, 0.f, 0.f, 0.f};

  for (int t = (int)blockIdx.x; t < NT; t += (int)gridDim.x) {
    const int base = t * 128 + w * 32;
    // tile-row remap: A-tile mt, row c  <->  edge base + 2*c + mt
    // (gives each lane 8 CONSECUTIVE edges in the epilogue)
    const int e0 = base + 2 * c, e1 = e0 + 1;
    int s0, s1, d0, d1;
    float dd0, dd1;
    if (SORTED) {
      s0 = src_s[e0]; s1 = src_s[e1];
      d0 = dst_s[e0]; d1 = dst_s[e1];
      dd0 = dist_s[e0]; dd1 = dist_s[e1];
    } else {
      s0 = eidx[e0]; s1 = eidx[e1];
      d0 = eidx[E_CNT + e0]; d1 = eidx[E_CNT + e1];
      dd0 = edist[e0]; dd1 = edist[e1];
    }

    f32x4 acc[2][8];
#pragma unroll
    for (int mt = 0; mt < 2; ++mt)
#pragma unroll
      for (int nt = 0; nt < 8; ++nt) acc[mt][nt] = vzero;

#pragma unroll
    for (int kt = 0; kt < 5; ++kt) {
      bf16x8 a0, a1;
      if (kt < 4) {
        const size_t r0 = (size_t)((kt < 2) ? s0 : d0) * 64 + (kt & 1) * 32 + g * 8;
        const size_t r1 = (size_t)((kt < 2) ? s1 : d1) * 64 + (kt & 1) * 32 + g * 8;
        if (SORTED) {
          a0 = *(const bf16x8*)&hb[r0];
          a1 = *(const bf16x8*)&hb[r1];
        } else {
          const f32x4 pa = *(const f32x4*)(h + r0), pb = *(const f32x4*)(h + r0 + 4);
          const f32x4 qa = *(const f32x4*)(h + r1), qb = *(const f32x4*)(h + r1 + 4);
          u32x4 u0 = {pack2(pa[0], pa[1]), pack2(pa[2], pa[3]),
                      pack2(pb[0], pb[1]), pack2(pb[2], pb[3])};
          u32x4 u1 = {pack2(qa[0], qa[1]), pack2(qa[2], qa[3]),
                      pack2(qb[0], qb[1]), pack2(qb[2], qb[3])};
          a0 = __builtin_bit_cast(bf16x8, u0);
          a1 = __builtin_bit_cast(bf16x8, u1);
        }
      } else {
#pragma unroll
        for (int j = 0; j < 8; ++j) {
          a0[j] = f2bf(silu_f(fmaf(dd0, we1s[j], be1s[j])));
          a1[j] = f2bf(silu_f(fmaf(dd1, we1s[j], be1s[j])));
        }
      }
      const int koff = kt * 32 + g * 8;
      const int swz = (kt < 4) ? ((c & 7) << 3) : ((c & 3) << 3);
#pragma unroll
      for (int nt = 0; nt < 8; ++nt) {
        const bf16x8 b = *(const bf16x8*)&ldsw[(nt * 16 + c) * 160 + (koff ^ swz)];
        acc[0][nt] = __builtin_amdgcn_mfma_f32_16x16x32_bf16(a0, b, acc[0][nt], 0, 0, 0);
        acc[1][nt] = __builtin_amdgcn_mfma_f32_16x16x32_bf16(a1, b, acc[1][nt], 0, 0, 0);
      }
    }

    f32x4 acc2[2][4];
#pragma unroll
    for (int nt = 0; nt < 4; ++nt) { acc2[0][nt] = vzero; acc2[1][nt] = vzero; }

#pragma unroll
    for (int mt = 0; mt < 2; ++mt) {
#pragma unroll
      for (int nt = 0; nt < 8; ++nt)
#pragma unroll
        for (int r = 0; r < 4; ++r)
          myscr[(g * 4 + r) * 136 + nt * 16 + c] = f2bf(silu_f(acc[mt][nt][r] + bias1[nt]));

#pragma unroll
      for (int kt = 0; kt < 4; ++kt) {
        const bf16x8 a2 = *(const bf16x8*)&myscr[c * 136 + kt * 32 + g * 8];
#pragma unroll
        for (int nt = 0; nt < 4; ++nt)
          acc2[mt][nt] = __builtin_amdgcn_mfma_f32_16x16x32_bf16(a2, wf[nt][kt], acc2[mt][nt], 0, 0, 0);
      }
    }

    // epilogue: lane (g,c) owns edges base+8g .. base+8g+7 (consecutive when
    // sorted) -> run-length reduce equal-dst before atomics.
    int des[8];
#pragma unroll
    for (int s = 0; s < 8; ++s)
      des[s] = __shfl((s & 1) ? d1 : d0, 4 * g + (s >> 1));

    float run[4];
    int cur = des[0];
#pragma unroll
    for (int nt = 0; nt < 4; ++nt) run[nt] = acc2[0][nt][0] + bias2[nt];
#pragma unroll
    for (int s = 1; s < 8; ++s) {
      const int mt = s & 1, r = s >> 1;
      if (des[s] == cur) {
#pragma unroll
        for (int nt = 0; nt < 4; ++nt) run[nt] += acc2[mt][nt][r] + bias2[nt];
      } else {
#pragma unroll
        for (int nt = 0; nt < 4; ++nt)
          unsafeAtomicAdd(&out[(size_t)cur * 64 + nt * 16 + c], run[nt]);
        cur = des[s];
#pragma unroll
        for (int nt = 0; nt < 4; ++nt) run[nt] = acc2[mt][nt][r] + bias2[nt];
      }
    }
#pragma unroll
    for (int nt = 0; nt < 4; ++nt)
      unsafeAtomicAdd(&out[(size_t)cur * 64 + nt * 16 + c], run[nt]);
  }
}

template <bool SORTED>
__global__ __launch_bounds__(256, 2) void k_coord(
    const float* __restrict__ h, const short* __restrict__ hb,
    const float* __restrict__ x, const float* __restrict__ edist,
    const float* __restrict__ We1, const float* __restrict__ be1,
    const float* __restrict__ We2, const float* __restrict__ be2,
    const float* __restrict__ Wc1, const float* __restrict__ bc1,
    const float* __restrict__ Wc2,
    const int* __restrict__ eidx,
    const int* __restrict__ src_s, const int* __restrict__ dst_s,
    const float* __restrict__ dist_s, float* __restrict__ xo) {
  __shared__ __align__(16) short ldsw[128 * 160];
  stage_weights(ldsw, Wc1, We2);
  __syncthreads();

  const int tid = (int)threadIdx.x;
  const int w = tid >> 6, l = tid & 63, g = l >> 4, c = l & 15;

  float we1s[8], be1s[8];
#pragma unroll
  for (int j = 0; j < 8; ++j) { we1s[j] = We1[g * 8 + j]; be1s[j] = be1[g * 8 + j]; }

  float bias1[8], wc2l[8];
#pragma unroll
  for (int nt = 0; nt < 8; ++nt) {
    const int colf = nt * 16 + c;
    float s = bc1[colf];
    for (int cc = 0; cc < 32; ++cc) s = fmaf(be2[cc], Wc1[(128 + cc) * 128 + colf], s);
    bias1[nt] = s;
    wc2l[nt] = Wc2[colf];
  }

  const f32x4 vzero = {0.f, 0.f, 0.f, 0.f};

  for (int t = (int)blockIdx.x; t < NT; t += (int)gridDim.x) {
    const int base = t * 128 + w * 32;
    const int e0 = base + c, e1 = e0 + 16;
    int s0, s1, d0, d1;
    float dd0, dd1;
    if (SORTED) {
      s0 = src_s[e0]; s1 = src_s[e1];
      d0 = dst_s[e0]; d1 = dst_s[e1];
      dd0 = dist_s[e0]; dd1 = dist_s[e1];
    } else {
      s0 = eidx[e0]; s1 = eidx[e1];
      d0 = eidx[E_CNT + e0]; d1 = eidx[E_CNT + e1];
      dd0 = edist[e0]; dd1 = edist[e1];
    }

    f32x4 acc[2][8];
#pragma unroll
    for (int mt = 0; mt < 2; ++mt)
#pragma unroll
      for (int nt = 0; nt < 8; ++nt) acc[mt][nt] = vzero;

#pragma unroll
    for (int kt = 0; kt < 5; ++kt) {
      bf16x8 a0, a1;
      if (kt < 4) {
        const size_t r0 = (size_t)((kt < 2) ? s0 : d0) * 64 + (kt & 1) * 32 + g * 8;
        const size_t r1 = (size_t)((kt < 2) ? s1 : d1) * 64 + (kt & 1) * 32 + g * 8;
        if (SORTED) {
          a0 = *(const bf16x8*)&hb[r0];
          a1 = *(const bf16x8*)&hb[r1];
        } else {
          const f32x4 pa = *(const f32x4*)(h + r0), pb = *(const f32x4*)(h + r0 + 4);
          const f32x4 qa = *(const f32x4*)(h + r1), qb = *(const f32x4*)(h + r1 + 4);
          u32x4 u0 = {pack2(pa[0], pa[1]), pack2(pa[2], pa[3]),
                      pack2(pb[0], pb[1]), pack2(pb[2], pb[3])};
          u32x4 u1 = {pack2(qa[0], qa[1]), pack2(qa[2], qa[3]),
                      pack2(qb[0], qb[1]), pack2(qb[2], qb[3])};
          a0 = __builtin_bit_cast(bf16x8, u0);
          a1 = __builtin_bit_cast(bf16x8, u1);
        }
      } else {
#pragma unroll
        for (int j = 0; j < 8; ++j) {
          a0[j] = f2bf(silu_f(fmaf(dd0, we1s[j], be1s[j])));
          a1[j] = f2bf(silu_f(fmaf(dd1, we1s[j], be1s[j])));
        }
      }
      const int koff = kt * 32 + g * 8;
      const int swz = (kt < 4) ? ((c & 7) << 3) : ((c & 3) << 3);
#pragma unroll
      for (int nt = 0; nt < 8; ++nt) {
        const bf16x8 b = *(const bf16x8*)&ldsw[(nt * 16 + c) * 160 + (koff ^ swz)];
        acc[0][nt] = __builtin_amdgcn_mfma_f32_16x16x32_bf16(a0, b, acc[0][nt], 0, 0, 0);
        acc[1][nt] = __builtin_amdgcn_mfma_f32_16x16x32_bf16(a1, b, acc[1][nt], 0, 0, 0);
      }
    }

#pragma unroll
    for (int mt = 0; mt < 2; ++mt) {
      float p[4] = {0.f, 0.f, 0.f, 0.f};
#pragma unroll
      for (int nt = 0; nt < 8; ++nt)
#pragma unroll
        for (int r = 0; r < 4; ++r)
          p[r] += silu_f(acc[mt][nt][r] + bias1[nt]) * wc2l[nt];
#pragma unroll
      for (int m = 1; m < 16; m <<= 1)
#pragma unroll
        for (int r = 0; r < 4; ++r) p[r] += __shfl_xor(p[r], m);

      const int srcm = mt ? s1 : s0;
      const int dstm = mt ? d1 : d0;
      const int el = (g * 4 + c) & 15;
      const int se = __shfl(srcm, el);
      const int de = __shfl(dstm, el);
      const float cw = (c == 0) ? p[0] : (c == 1) ? p[1] : (c == 2) ? p[2] : p[3];
      if (c < 4) {
        const float ax = x[se * 3 + 0] - x[de * 3 + 0];
        const float ay = x[se * 3 + 1] - x[de * 3 + 1];
        const float az = x[se * 3 + 2] - x[de * 3 + 2];
        float len = sqrtf(fmaf(ax, ax, fmaf(ay, ay, az * az)));
        len = fmaxf(len, 1e-8f);
        const float scl = cw / len;
        unsafeAtomicAdd(&xo[de * 3 + 0], scl * ax);
        unsafeAtomicAdd(&xo[de * 3 + 1], scl * ay);
        unsafeAtomicAdd(&xo[de * 3 + 2], scl * az);
      }
    }
  }
}

extern "C" void kernel_launch(void* const* d_in, const int* in_sizes, int n_in,
                              void* d_out, int out_size, void* d_ws, size_t ws_size,
                              hipStream_t stream) {
  const float* h = (const float*)d_in[0];
  const float* x = (const float*)d_in[1];
  const float* edist = (const float*)d_in[2];
  const float* We1 = (const float*)d_in[3];
  const float* be1 = (const float*)d_in[4];
  const float* We2 = (const float*)d_in[5];
  const float* be2 = (const float*)d_in[6];
  const float* Wn1 = (const float*)d_in[7];
  const float* bn1 = (const float*)d_in[8];
  const float* Wn2 = (const float*)d_in[9];
  const float* bn2 = (const float*)d_in[10];
  const float* Wc1 = (const float*)d_in[11];
  const float* bc1 = (const float*)d_in[12];
  const float* Wc2 = (const float*)d_in[13];
  const int* eidx = (const int*)d_in[14];
  float* out = (float*)d_out;
  float* xo = out + 3200000;

  char* wsb = (char*)d_ws;
  int* cursor = (int*)wsb;                  // 200 KB (padded to 200704)
  int* src_s = (int*)(wsb + 200704);        // 3.2 MB
  int* dst_s = (int*)(wsb + 3400704);       // 3.2 MB
  float* dist_s = (float*)(wsb + 6600704);  // 3.2 MB
  short* hb = (short*)(wsb + 9800704);      // 6.4 MB -> 16200704 total
  const bool sorted = (ws_size >= (size_t)16200704);

  if (sorted) {
    hipMemsetAsync(cursor, 0, N_CNT * sizeof(int), stream);
    k_init<<<dim3(3272), dim3(256), 0, stream>>>(h, x, out, hb);
    k_hist<<<dim3(3125), dim3(256), 0, stream>>>(eidx, cursor);
    k_scan<<<dim3(1), dim3(1024), 0, stream>>>(cursor);
    k_fill<<<dim3(3125), dim3(256), 0, stream>>>(eidx, edist, cursor, src_s, dst_s, dist_s);
    k_node<true><<<dim3(512), dim3(256), 0, stream>>>(h, hb, edist, We1, be1, We2, be2,
                                                      Wn1, bn1, Wn2, bn2, eidx,
                                                      src_s, dst_s, dist_s, out);
    k_coord<true><<<dim3(512), dim3(256), 0, stream>>>(h, hb, x, edist, We1, be1, We2, be2,
                                                       Wc1, bc1, Wc2, eidx,
                                                       src_s, dst_s, dist_s, xo);
  } else {
    k_init<<<dim3(3272), dim3(256), 0, stream>>>(h, x, out, nullptr);
    k_node<false><<<dim3(512), dim3(256), 0, stream>>>(h, nullptr, edist, We1, be1, We2, be2,
                                                       Wn1, bn1, Wn2, bn2, eidx,
                                                       nullptr, nullptr, nullptr, out);
    k_coord<false><<<dim3(512), dim3(256), 0, stream>>>(h, nullptr, x, edist, We1, be1, We2, be2,
                                                        Wc1, bc1, Wc2, eidx,
                                                        nullptr, nullptr, nullptr, xo);
  }
}

// Round 5
// 524.301 us; speedup vs baseline: 1.8193x; 1.1868x over previous
//
#include <hip/hip_runtime.h>
#include <cstdint>
#include <cstddef>

#define E_CNT 800000
#define N_CNT 50000
#define NT 6250  // tiles of 128 edges

typedef short bf16x8 __attribute__((ext_vector_type(8)));
typedef short s16x4 __attribute__((ext_vector_type(4)));
typedef float f32x4 __attribute__((ext_vector_type(4)));
typedef uint32_t u32x4 __attribute__((ext_vector_type(4)));

// ws byte offsets
#define OFF_CURSOR 0
#define OFF_WFN 200064
#define OFF_WFC 241024
#define OFF_W2F 281984
#define OFF_BIASN 298368
#define OFF_BIASC 298880
#define OFF_SRC 299520
#define OFF_DST 3499520
#define OFF_DIST 6699520
#define OFF_HB 8299520
#define REQ_FULL 14699520
#define REQ_W 299392

__device__ __forceinline__ short f2bf(float v) {
  uint32_t u = __builtin_bit_cast(uint32_t, v);
  u = (u + 0x7FFFu + ((u >> 16) & 1u)) >> 16;
  return (short)u;
}
__device__ __forceinline__ float bf2f(short s) {
  uint32_t u = ((uint32_t)(uint16_t)s) << 16;
  return __builtin_bit_cast(float, u);
}
__device__ __forceinline__ uint32_t pack2(float lo, float hi) {
  return ((uint32_t)(uint16_t)f2bf(hi) << 16) | (uint32_t)(uint16_t)f2bf(lo);
}
__device__ __forceinline__ float silu_f(float v) {
  return v * (1.0f / (1.0f + __expf(-v)));
}

__global__ void k_init(const float* __restrict__ h, const float* __restrict__ x,
                       float* __restrict__ out, short* __restrict__ hb) {
  const int i = (int)(blockIdx.x * 256 + threadIdx.x);
  if (i < 800000) {
    const f32x4 v = ((const f32x4*)h)[i];
    ((f32x4*)out)[i] = v;
    if (hb) {
      s16x4 p;
#pragma unroll
      for (int j = 0; j < 4; ++j) p[j] = f2bf(v[j]);
      *(s16x4*)(hb + i * 4) = p;
    }
  } else if (i < 837500) {
    ((f32x4*)out)[i] = ((const f32x4*)x)[i - 800000];
  }
}

// Fragment-linear weight prep. frag layout: Wf[(fid*64 + lane)*8 + j].
// GEMM1 frag (fid = kt*8+nt): lane l -> Weff^T[nt*16+(l&15)][kt*32+(l>>4)*8+j]
//   Weff^T[row][k] = W1[k*128+row] (k<128) | fold We2 (k>=128)
// GEMM2 frag (fid = kt2*4+nt2): lane l -> Wn2[(kt2*32+(l>>4)*8+j)*64 + nt2*16+(l&15)]
__global__ void k_wprep(const float* __restrict__ W1n, const float* __restrict__ W1c,
                        const float* __restrict__ We2, const float* __restrict__ bn1,
                        const float* __restrict__ bc1, const float* __restrict__ be2,
                        const float* __restrict__ Wn2,
                        short* __restrict__ Wfn, short* __restrict__ Wfc,
                        short* __restrict__ W2f, float* __restrict__ biasn,
                        float* __restrict__ biasc) {
  const int b = (int)blockIdx.x;  // 0..39 Wfn, 40..79 Wfc, 80..95 W2f, 96 biases
  const int l = (int)threadIdx.x; // 64
  if (b < 80) {
    const int fid = (b < 40) ? b : (b - 40);
    const float* W1 = (b < 40) ? W1n : W1c;
    short* Wf = (b < 40) ? Wfn : Wfc;
    const int kt = fid >> 3, nt = fid & 7;
    const int row = nt * 16 + (l & 15);
    const int k0 = kt * 32 + (l >> 4) * 8;
    bf16x8 v;
#pragma unroll
    for (int j = 0; j < 8; ++j) {
      const int k = k0 + j;
      float val;
      if (k < 128) {
        val = W1[k * 128 + row];
      } else {
        float s = 0.f;
        for (int cc = 0; cc < 32; ++cc)
          s = fmaf(We2[(k - 128) * 32 + cc], W1[(128 + cc) * 128 + row], s);
        val = s;
      }
      v[j] = f2bf(val);
    }
    *(bf16x8*)&Wf[(fid * 64 + l) * 8] = v;
  } else if (b < 96) {
    const int fid = b - 80;
    const int kt2 = fid >> 2, nt2 = fid & 3;
    bf16x8 v;
#pragma unroll
    for (int j = 0; j < 8; ++j)
      v[j] = f2bf(Wn2[(kt2 * 32 + (l >> 4) * 8 + j) * 64 + nt2 * 16 + (l & 15)]);
    *(bf16x8*)&W2f[(fid * 64 + l) * 8] = v;
  } else {
    for (int col = l; col < 128; col += 64) {
      float sn = bn1[col], sc = bc1[col];
      for (int cc = 0; cc < 32; ++cc) {
        sn = fmaf(be2[cc], W1n[(128 + cc) * 128 + col], sn);
        sc = fmaf(be2[cc], W1c[(128 + cc) * 128 + col], sc);
      }
      biasn[col] = sn;
      biasc[col] = sc;
    }
  }
}

__global__ void k_hist(const int* __restrict__ eidx, int* __restrict__ cursor) {
  const int e = (int)(blockIdx.x * 256 + threadIdx.x);
  if (e < E_CNT) atomicAdd(&cursor[eidx[E_CNT + e]], 1);
}

__global__ __launch_bounds__(1024) void k_scan(int* __restrict__ cursor) {
  __shared__ int part[1024];
  const int t = (int)threadIdx.x;
  const int b0 = t * 49;
  int n = N_CNT - b0;
  n = n < 0 ? 0 : (n > 49 ? 49 : n);
  int s = 0;
  for (int i = 0; i < n; ++i) s += cursor[b0 + i];
  part[t] = s;
  __syncthreads();
  for (int off = 1; off < 1024; off <<= 1) {
    const int u = (t >= off) ? part[t - off] : 0;
    __syncthreads();
    part[t] += u;
    __syncthreads();
  }
  int run = (t == 0) ? 0 : part[t - 1];
  for (int i = 0; i < n; ++i) {
    const int old = cursor[b0 + i];
    cursor[b0 + i] = run;
    run += old;
  }
}

__global__ void k_fill(const int* __restrict__ eidx, const float* __restrict__ edist,
                       int* __restrict__ cursor, int* __restrict__ src_s,
                       int* __restrict__ dst_s, short* __restrict__ dist_s) {
  const int e = (int)(blockIdx.x * 256 + threadIdx.x);
  if (e < E_CNT) {
    const int d = eidx[E_CNT + e];
    const int pos = atomicAdd(&cursor[d], 1);
    src_s[pos] = eidx[e];
    dst_s[pos] = d;
    dist_s[pos] = f2bf(edist[e]);
  }
}

template <bool SORTED>
__global__ __launch_bounds__(256, 2) void k_node(
    const float* __restrict__ h, const short* __restrict__ hb,
    const float* __restrict__ edist,
    const float* __restrict__ We1, const float* __restrict__ be1,
    const float* __restrict__ bn2, const int* __restrict__ eidx,
    const int* __restrict__ src_s, const int* __restrict__ dst_s,
    const short* __restrict__ dist_s,
    const short* __restrict__ Wf, const short* __restrict__ W2f,
    const float* __restrict__ biasn, float* __restrict__ out) {
  __shared__ __align__(16) short scr[4][16 * 136];

  const int tid = (int)threadIdx.x;
  const int w = tid >> 6, l = tid & 63, g = l >> 4, c = l & 15;
  short* myscr = &scr[w][0];

  float we1s[8], be1s[8];
#pragma unroll
  for (int j = 0; j < 8; ++j) { we1s[j] = We1[g * 8 + j]; be1s[j] = be1[g * 8 + j]; }
  float bias1[8];
#pragma unroll
  for (int nt = 0; nt < 8; ++nt) bias1[nt] = biasn[nt * 16 + c];
  float bias2[4];
#pragma unroll
  for (int nt = 0; nt < 4; ++nt) bias2[nt] = bn2[nt * 16 + c];

  const f32x4 vzero = {0.f, 0.f, 0.f, 0.f};

  for (int t = (int)blockIdx.x; t < NT; t += (int)gridDim.x) {
    // defeat LICM on the frag tables (would hoist ~200 VGPRs of loads)
    const short* wft = Wf;
    const short* w2t = W2f;
    asm volatile("" : "+v"(wft), "+v"(w2t));

    const int base = t * 128 + w * 32;
    // tile-row remap: A-tile mt, row c <-> edge base + 2*c + mt
    const int e0 = base + 2 * c, e1 = e0 + 1;
    int s0, s1, d0, d1;
    float dd0, dd1;
    if (SORTED) {
      s0 = src_s[e0]; s1 = src_s[e1];
      d0 = dst_s[e0]; d1 = dst_s[e1];
      dd0 = bf2f(dist_s[e0]); dd1 = bf2f(dist_s[e1]);
    } else {
      s0 = eidx[e0]; s1 = eidx[e1];
      d0 = eidx[E_CNT + e0]; d1 = eidx[E_CNT + e1];
      dd0 = edist[e0]; dd1 = edist[e1];
    }

    f32x4 acc[2][8];
#pragma unroll
    for (int mt = 0; mt < 2; ++mt)
#pragma unroll
      for (int nt = 0; nt < 8; ++nt) acc[mt][nt] = vzero;

#pragma unroll
    for (int kt = 0; kt < 5; ++kt) {
      bf16x8 a0, a1;
      if (kt < 4) {
        const size_t r0 = (size_t)((kt < 2) ? s0 : d0) * 64 + (kt & 1) * 32 + g * 8;
        const size_t r1 = (size_t)((kt < 2) ? s1 : d1) * 64 + (kt & 1) * 32 + g * 8;
        if (SORTED) {
          a0 = *(const bf16x8*)&hb[r0];
          a1 = *(const bf16x8*)&hb[r1];
        } else {
          const f32x4 pa = *(const f32x4*)(h + r0), pb = *(const f32x4*)(h + r0 + 4);
          const f32x4 qa = *(const f32x4*)(h + r1), qb = *(const f32x4*)(h + r1 + 4);
          u32x4 u0 = {pack2(pa[0], pa[1]), pack2(pa[2], pa[3]),
                      pack2(pb[0], pb[1]), pack2(pb[2], pb[3])};
          u32x4 u1 = {pack2(qa[0], qa[1]), pack2(qa[2], qa[3]),
                      pack2(qb[0], qb[1]), pack2(qb[2], qb[3])};
          a0 = __builtin_bit_cast(bf16x8, u0);
          a1 = __builtin_bit_cast(bf16x8, u1);
        }
      } else {
#pragma unroll
        for (int j = 0; j < 8; ++j) {
          a0[j] = f2bf(silu_f(fmaf(dd0, we1s[j], be1s[j])));
          a1[j] = f2bf(silu_f(fmaf(dd1, we1s[j], be1s[j])));
        }
      }
#pragma unroll
      for (int nt = 0; nt < 8; ++nt) {
        const bf16x8 b = *(const bf16x8*)&wft[(((kt << 3) + nt) << 9) + (l << 3)];
        acc[0][nt] = __builtin_amdgcn_mfma_f32_16x16x32_bf16(a0, b, acc[0][nt], 0, 0, 0);
        acc[1][nt] = __builtin_amdgcn_mfma_f32_16x16x32_bf16(a1, b, acc[1][nt], 0, 0, 0);
      }
    }

    f32x4 acc2[2][4];
#pragma unroll
    for (int nt = 0; nt < 4; ++nt) { acc2[0][nt] = vzero; acc2[1][nt] = vzero; }

#pragma unroll
    for (int mt = 0; mt < 2; ++mt) {
#pragma unroll
      for (int nt = 0; nt < 8; ++nt)
#pragma unroll
        for (int r = 0; r < 4; ++r)
          myscr[(g * 4 + r) * 136 + nt * 16 + c] = f2bf(silu_f(acc[mt][nt][r] + bias1[nt]));

#pragma unroll
      for (int kt2 = 0; kt2 < 4; ++kt2) {
        const bf16x8 a2 = *(const bf16x8*)&myscr[c * 136 + kt2 * 32 + g * 8];
#pragma unroll
        for (int nt2 = 0; nt2 < 4; ++nt2) {
          const bf16x8 b2 = *(const bf16x8*)&w2t[(((kt2 << 2) + nt2) << 9) + (l << 3)];
          acc2[mt][nt2] = __builtin_amdgcn_mfma_f32_16x16x32_bf16(a2, b2, acc2[mt][nt2], 0, 0, 0);
        }
      }
    }

    // RLE epilogue: lane (g,c) owns 8 consecutive edges base+8g..base+8g+7
    int des[8];
#pragma unroll
    for (int s = 0; s < 8; ++s)
      des[s] = __shfl((s & 1) ? d1 : d0, 4 * g + (s >> 1));

    float run[4];
    int cur = des[0];
#pragma unroll
    for (int nt = 0; nt < 4; ++nt) run[nt] = acc2[0][nt][0] + bias2[nt];
#pragma unroll
    for (int s = 1; s < 8; ++s) {
      const int mt = s & 1, r = s >> 1;
      if (des[s] == cur) {
#pragma unroll
        for (int nt = 0; nt < 4; ++nt) run[nt] += acc2[mt][nt][r] + bias2[nt];
      } else {
#pragma unroll
        for (int nt = 0; nt < 4; ++nt)
          unsafeAtomicAdd(&out[(size_t)cur * 64 + nt * 16 + c], run[nt]);
        cur = des[s];
#pragma unroll
        for (int nt = 0; nt < 4; ++nt) run[nt] = acc2[mt][nt][r] + bias2[nt];
      }
    }
#pragma unroll
    for (int nt = 0; nt < 4; ++nt)
      unsafeAtomicAdd(&out[(size_t)cur * 64 + nt * 16 + c], run[nt]);
  }
}

template <bool BF>
__global__ __launch_bounds__(256, 2) void k_coord(
    const float* __restrict__ h, const short* __restrict__ hb,
    const float* __restrict__ x, const float* __restrict__ edist,
    const float* __restrict__ We1, const float* __restrict__ be1,
    const float* __restrict__ Wc2, const int* __restrict__ eidx,
    const short* __restrict__ Wf, const float* __restrict__ biasc,
    float* __restrict__ xo) {
  const int tid = (int)threadIdx.x;
  const int w = tid >> 6, l = tid & 63, g = l >> 4, c = l & 15;

  float we1s[8], be1s[8];
#pragma unroll
  for (int j = 0; j < 8; ++j) { we1s[j] = We1[g * 8 + j]; be1s[j] = be1[g * 8 + j]; }
  float bias1[8], wc2l[8];
#pragma unroll
  for (int nt = 0; nt < 8; ++nt) {
    bias1[nt] = biasc[nt * 16 + c];
    wc2l[nt] = Wc2[nt * 16 + c];
  }

  const f32x4 vzero = {0.f, 0.f, 0.f, 0.f};

  for (int t = (int)blockIdx.x; t < NT; t += (int)gridDim.x) {
    const short* wft = Wf;
    asm volatile("" : "+v"(wft));

    const int base = t * 128 + w * 32;
    const int e0 = base + c, e1 = e0 + 16;
    const int s0 = eidx[e0], s1 = eidx[e1];
    const int d0 = eidx[E_CNT + e0], d1 = eidx[E_CNT + e1];
    const float dd0 = edist[e0], dd1 = edist[e1];

    f32x4 acc[2][8];
#pragma unroll
    for (int mt = 0; mt < 2; ++mt)
#pragma unroll
      for (int nt = 0; nt < 8; ++nt) acc[mt][nt] = vzero;

#pragma unroll
    for (int kt = 0; kt < 5; ++kt) {
      bf16x8 a0, a1;
      if (kt < 4) {
        const size_t r0 = (size_t)((kt < 2) ? s0 : d0) * 64 + (kt & 1) * 32 + g * 8;
        const size_t r1 = (size_t)((kt < 2) ? s1 : d1) * 64 + (kt & 1) * 32 + g * 8;
        if (BF) {
          a0 = *(const bf16x8*)&hb[r0];
          a1 = *(const bf16x8*)&hb[r1];
        } else {
          const f32x4 pa = *(const f32x4*)(h + r0), pb = *(const f32x4*)(h + r0 + 4);
          const f32x4 qa = *(const f32x4*)(h + r1), qb = *(const f32x4*)(h + r1 + 4);
          u32x4 u0 = {pack2(pa[0], pa[1]), pack2(pa[2], pa[3]),
                      pack2(pb[0], pb[1]), pack2(pb[2], pb[3])};
          u32x4 u1 = {pack2(qa[0], qa[1]), pack2(qa[2], qa[3]),
                      pack2(qb[0], qb[1]), pack2(qb[2], qb[3])};
          a0 = __builtin_bit_cast(bf16x8, u0);
          a1 = __builtin_bit_cast(bf16x8, u1);
        }
      } else {
#pragma unroll
        for (int j = 0; j < 8; ++j) {
          a0[j] = f2bf(silu_f(fmaf(dd0, we1s[j], be1s[j])));
          a1[j] = f2bf(silu_f(fmaf(dd1, we1s[j], be1s[j])));
        }
      }
#pragma unroll
      for (int nt = 0; nt < 8; ++nt) {
        const bf16x8 b = *(const bf16x8*)&wft[(((kt << 3) + nt) << 9) + (l << 3)];
        acc[0][nt] = __builtin_amdgcn_mfma_f32_16x16x32_bf16(a0, b, acc[0][nt], 0, 0, 0);
        acc[1][nt] = __builtin_amdgcn_mfma_f32_16x16x32_bf16(a1, b, acc[1][nt], 0, 0, 0);
      }
    }

#pragma unroll
    for (int mt = 0; mt < 2; ++mt) {
      float p[4] = {0.f, 0.f, 0.f, 0.f};
#pragma unroll
      for (int nt = 0; nt < 8; ++nt)
#pragma unroll
        for (int r = 0; r < 4; ++r)
          p[r] += silu_f(acc[mt][nt][r] + bias1[nt]) * wc2l[nt];
#pragma unroll
      for (int m = 1; m < 16; m <<= 1)
#pragma unroll
        for (int r = 0; r < 4; ++r) p[r] += __shfl_xor(p[r], m);

      const int srcm = mt ? s1 : s0;
      const int dstm = mt ? d1 : d0;
      const int el = (g * 4 + c) & 15;
      const int se = __shfl(srcm, el);
      const int de = __shfl(dstm, el);
      const float cw = (c == 0) ? p[0] : (c == 1) ? p[1] : (c == 2) ? p[2] : p[3];
      if (c < 4) {
        const float ax = x[se * 3 + 0] - x[de * 3 + 0];
        const float ay = x[se * 3 + 1] - x[de * 3 + 1];
        const float az = x[se * 3 + 2] - x[de * 3 + 2];
        float len = sqrtf(fmaf(ax, ax, fmaf(ay, ay, az * az)));
        len = fmaxf(len, 1e-8f);
        const float scl = cw / len;
        unsafeAtomicAdd(&xo[de * 3 + 0], scl * ax);
        unsafeAtomicAdd(&xo[de * 3 + 1], scl * ay);
        unsafeAtomicAdd(&xo[de * 3 + 2], scl * az);
      }
    }
  }
}

extern "C" void kernel_launch(void* const* d_in, const int* in_sizes, int n_in,
                              void* d_out, int out_size, void* d_ws, size_t ws_size,
                              hipStream_t stream) {
  const float* h = (const float*)d_in[0];
  const float* x = (const float*)d_in[1];
  const float* edist = (const float*)d_in[2];
  const float* We1 = (const float*)d_in[3];
  const float* be1 = (const float*)d_in[4];
  const float* We2 = (const float*)d_in[5];
  const float* be2 = (const float*)d_in[6];
  const float* Wn1 = (const float*)d_in[7];
  const float* bn1 = (const float*)d_in[8];
  const float* Wn2 = (const float*)d_in[9];
  const float* bn2 = (const float*)d_in[10];
  const float* Wc1 = (const float*)d_in[11];
  const float* bc1 = (const float*)d_in[12];
  const float* Wc2 = (const float*)d_in[13];
  const int* eidx = (const int*)d_in[14];
  float* out = (float*)d_out;
  float* xo = out + 3200000;

  char* wsb = (char*)d_ws;
  int* cursor = (int*)(wsb + OFF_CURSOR);
  short* Wfn = (short*)(wsb + OFF_WFN);
  short* Wfc = (short*)(wsb + OFF_WFC);
  short* W2f = (short*)(wsb + OFF_W2F);
  float* biasn = (float*)(wsb + OFF_BIASN);
  float* biasc = (float*)(wsb + OFF_BIASC);
  int* src_s = (int*)(wsb + OFF_SRC);
  int* dst_s = (int*)(wsb + OFF_DST);
  short* dist_s = (short*)(wsb + OFF_DIST);
  short* hb = (short*)(wsb + OFF_HB);

  const bool full = (ws_size >= (size_t)REQ_FULL);

  k_wprep<<<dim3(97), dim3(64), 0, stream>>>(Wn1, Wc1, We2, bn1, bc1, be2, Wn2,
                                             Wfn, Wfc, W2f, biasn, biasc);
  if (full) {
    hipMemsetAsync(cursor, 0, N_CNT * sizeof(int), stream);
    k_init<<<dim3(3272), dim3(256), 0, stream>>>(h, x, out, hb);
    k_hist<<<dim3(3125), dim3(256), 0, stream>>>(eidx, cursor);
    k_scan<<<dim3(1), dim3(1024), 0, stream>>>(cursor);
    k_fill<<<dim3(3125), dim3(256), 0, stream>>>(eidx, edist, cursor, src_s, dst_s, dist_s);
    k_node<true><<<dim3(1024), dim3(256), 0, stream>>>(h, hb, edist, We1, be1, bn2, eidx,
                                                       src_s, dst_s, dist_s, Wfn, W2f,
                                                       biasn, out);
    k_coord<true><<<dim3(1024), dim3(256), 0, stream>>>(h, hb, x, edist, We1, be1, Wc2,
                                                        eidx, Wfc, biasc, xo);
  } else {
    k_init<<<dim3(3272), dim3(256), 0, stream>>>(h, x, out, nullptr);
    k_node<false><<<dim3(1024), dim3(256), 0, stream>>>(h, nullptr, edist, We1, be1, bn2,
                                                        eidx, nullptr, nullptr, nullptr,
                                                        Wfn, W2f, biasn, out);
    k_coord<false><<<dim3(1024), dim3(256), 0, stream>>>(h, nullptr, x, edist, We1, be1,
                                                         Wc2, eidx, Wfc, biasc, xo);
  }
}